// Round 5
// baseline (923.147 us; speedup 1.0000x reference)
//
#include <hip/hip_runtime.h>

// CTRNN forward, B=256 T=2048 D=32 H=64. ALL tensors fp32.
// r4 post-mortem: recur VGPR_Count=48 => W_hh was NOT register-resident (the
// compiler remat'd the weight loads inside the step loop under its default
// occupancy target). Fix: __launch_bounds__(64,1). xproj was ~300us due to
// 512 broadcast vector loads/wave through the TA pipe; fix: wave-uniform x
// addresses -> SMEM (s_load) broadcast + SGPR operand in v_fma.

#define Bb 256
#define Tt 2048
#define Dd 32
#define Hh 64

typedef float v2f __attribute__((ext_vector_type(2)));

static constexpr float ALPHA = (float)(16.67 / 40.0);
static constexpr float OMA   = 1.0f - ALPHA;

static __device__ inline v2f vfma2(v2f a, v2f b, v2f c) {
#if __has_builtin(__builtin_elementwise_fma)
    return __builtin_elementwise_fma(a, b, c);
#else
    v2f r; r.x = fmaf(a.x, b.x, c.x); r.y = fmaf(a.y, b.y, c.y); return r;
#endif
}

// ---------------- Phase A: out[b][t][h] = dot(x[b][t][:], W_in[h][:]) -------
// grid 2048 = 256 b x 8 tiles, block 256 (4 waves, each wave 64 t's).
// Lane h keeps W_in[h][:] in VGPRs. x[t][:] is wave-uniform -> compiler emits
// scalar s_load; the x value is the (single, legal) SGPR operand of v_fma.
// Stores coalesced (lane = fastest output dim). No LDS, no barriers.
__global__ __launch_bounds__(256) void ctrnn_xproj(
    const float* __restrict__ x,
    const float* __restrict__ W_in,
    float* __restrict__ out)
{
    const int lane = threadIdx.x & 63;
    const int wave = threadIdx.x >> 6;
    const int b    = blockIdx.x >> 3;
    const int tile = blockIdx.x & 7;
    const int t0   = tile * 256 + wave * 64;

    float w[Dd];
    const float* wrow = W_in + lane * Dd;
#pragma unroll
    for (int d = 0; d < Dd; ++d) w[d] = wrow[d];

    const float* xb = x + (size_t)b * Tt * Dd;
    float*       ob = out + (size_t)b * Tt * Hh;

#pragma unroll 2
    for (int i = 0; i < 64; ++i) {
        const int t = t0 + i;
        const float* xr = xb + (size_t)t * Dd;   // wave-uniform address
        float s0 = 0.f, s1 = 0.f, s2 = 0.f, s3 = 0.f;
#pragma unroll
        for (int d = 0; d < Dd; d += 4) {
            s0 = fmaf(w[d + 0], xr[d + 0], s0);
            s1 = fmaf(w[d + 1], xr[d + 1], s1);
            s2 = fmaf(w[d + 2], xr[d + 2], s2);
            s3 = fmaf(w[d + 3], xr[d + 3], s3);
        }
        ob[(size_t)t * Hh + lane] = (s0 + s1) + (s2 + s3);
    }
}

// ---------------- Phase B: sequential recurrence, 1 wave per batch ----------
// No __syncthreads anywhere: single wave, LDS deps ordered by lgkmcnt only.
// xp read from out rows (written by phase A), 8-deep register ring prefetch;
// row t is overwritten with h_t after its xp is consumed (same-lane ordering).
// __launch_bounds__(64,1): target 1 wave/EU so weights stay in VGPRs.
__global__ __launch_bounds__(64, 1) void ctrnn_recur(
    const float* __restrict__ b_in,
    const float* __restrict__ W_hh,
    const float* __restrict__ b_hh,
    float* __restrict__ out)
{
    const int b    = blockIdx.x;
    const int lane = threadIdx.x;

    __shared__ alignas(16) float hs[Hh];

    // W_hh row in registers as 32 v2f pairs (64 VGPRs).
    v2f w[Hh / 2];
    const v2f* wrow = reinterpret_cast<const v2f*>(W_hh + lane * Hh);
#pragma unroll
    for (int j = 0; j < Hh / 2; ++j) w[j] = wrow[j];
    const float cb = ALPHA * (b_in[lane] + b_hh[lane]);

    hs[lane] = 0.0f;   // single wave: ordered vs later ds_reads by lgkmcnt

    float* ob = out + (size_t)b * Tt * Hh + lane;

    float xp[8];
#pragma unroll
    for (int j = 0; j < 8; ++j) xp[j] = ob[(size_t)j * Hh];

    float hold = 0.0f;
    for (int t = 0; t < Tt; t += 8) {
#pragma unroll
        for (int j = 0; j < 8; ++j) {
            const float xpj = xp[j];
            // refill ring 8 ahead (stays in-bounds: rows past Tt land in the
            // hlast region / next batch rows; value never consumed)
            xp[j] = ob[(size_t)(t + j + 8) * Hh];

            // matvec: lane h computes sum_k W_hh[h][k] * hs[k] (broadcast reads)
            const float4* h4 = reinterpret_cast<const float4*>(hs);
            v2f acc0 = {0.f, 0.f}, acc1 = {0.f, 0.f};
#pragma unroll
            for (int k = 0; k < 16; ++k) {
                const float4 hv = h4[k];
                const v2f h01 = {hv.x, hv.y};
                const v2f h23 = {hv.z, hv.w};
                acc0 = vfma2(w[2 * k + 0], h01, acc0);
                acc1 = vfma2(w[2 * k + 1], h23, acc1);
            }
            const v2f accs = acc0 + acc1;
            const float sum = (accs.x + accs.y) + xpj;
            const float hnew = fmaxf(fmaf(ALPHA, sum, fmaf(OMA, hold, cb)), 0.0f);

            hs[lane] = hnew;                        // next step's broadcast src
            ob[(size_t)(t + j) * Hh] = hnew;        // overwrite xp row with h
            hold = hnew;
        }
    }
    // h_last
    out[(size_t)Bb * Tt * Hh + (size_t)b * Hh + lane] = hold;
}

extern "C" void kernel_launch(void* const* d_in, const int* in_sizes, int n_in,
                              void* d_out, int out_size, void* d_ws, size_t ws_size,
                              hipStream_t stream) {
    const float* x    = (const float*)d_in[0];
    // d_in[1] = seq_lengths (int32): forward value is mask-independent.
    const float* W_in = (const float*)d_in[2];
    const float* b_in = (const float*)d_in[3];
    const float* W_hh = (const float*)d_in[4];
    const float* b_hh = (const float*)d_in[5];
    float* out = (float*)d_out;

    ctrnn_xproj<<<dim3(Bb * 8), dim3(256), 0, stream>>>(x, W_in, out);
    ctrnn_recur<<<dim3(Bb), dim3(64), 0, stream>>>(b_in, W_hh, b_hh, out);
}